// Round 11
// baseline (173.405 us; speedup 1.0000x reference)
//
#include <hip/hip_runtime.h>
#include <math.h>

#define L 256
#define E 128
#define H 4
#define C 32
#define P (L*L)  // 65536

typedef __bf16 bf16;
typedef __bf16 bf16x8 __attribute__((ext_vector_type(8)));
typedef __bf16 bf16x4 __attribute__((ext_vector_type(4)));
typedef float  f32x4  __attribute__((ext_vector_type(4)));

#define MFMA(a,b,c) __builtin_amdgcn_mfma_f32_16x16x32_bf16((a),(b),(c),0,0,0)

// ---------------------------------------------------------------------------
// k_prep: emit weights in MFMA A-fragment order. Grid 41: blocks 0..39 cover
// (m, frag-quad) with one fragment per wave; block 40 builds WbF.
// ---------------------------------------------------------------------------
__global__ __launch_bounds__(256) void k_prep(
    const float* __restrict__ Wq, const float* __restrict__ Wk,
    const float* __restrict__ Wv, const float* __restrict__ Wfu,
    const float* __restrict__ Wo, const float* __restrict__ Wb,
    bf16* __restrict__ WF, bf16* __restrict__ WoF, bf16* __restrict__ WbF)
{
  const int b = blockIdx.x;  // 0..40
  const int lane = threadIdx.x & 63, wv = threadIdx.x >> 6;
  const int g = lane >> 4, l15 = lane & 15;
  if (b < 40) {
    const int m = b >> 3;
    const int f = (b & 7) * 4 + wv;
    const float* W = (m==0)?Wq:(m==1)?Wk:(m==2)?Wv:(m==3)?Wfu:Wo;
    bf16* dst = (m < 4) ? (WF + (size_t)m * 16384) : WoF;
    const float sc = (m == 0) ? 0.17677669529663689f : 1.0f;
    const int mt = f >> 2, kt = f & 3;
    const int row = 16*mt + l15, k0 = 32*kt + 8*g;
    bf16x8 o;
    #pragma unroll
    for (int j = 0; j < 8; ++j) o[j] = (bf16)(W[(size_t)(k0+j)*128 + row] * sc);
    *(bf16x8*)(dst + ((size_t)f*64 + lane)*8) = o;
  } else {
    const int kt = wv, k0 = 32*kt + 8*g;
    bf16x8 o;
    #pragma unroll
    for (int j = 0; j < 8; ++j)
      o[j] = (l15 < 4) ? (bf16)Wb[(size_t)(k0+j)*4 + l15] : (bf16)0.0f;
    *(bf16x8*)(WbF + ((size_t)kt*64 + lane)*8) = o;
  }
}

// ---------------------------------------------------------------------------
// k_ln_proj: 512 threads = 8 waves, 64 positions/block; position-major
// [P][128] outputs (128B-contiguous stores). NEW: writes T5 directly from the
// pair-bias MFMA registers (T5[h][pos] = mask[pos] + pb[pos][h]) -- the
// entire k_bias kernel + pbo round-trip is eliminated.
// Wave (m = w&3, half = w>>2) computes cols [64*half..) of matrix m.
// ---------------------------------------------------------------------------
__global__ __launch_bounds__(512) void k_ln_proj(
    const float* __restrict__ pr, const float* __restrict__ gamma,
    const float* __restrict__ beta, const float* __restrict__ bfu,
    const bf16* __restrict__ WF, const bf16* __restrict__ WbF,
    const float* __restrict__ mask,
    bf16* __restrict__ qb, bf16* __restrict__ kb, bf16* __restrict__ vb,
    bf16* __restrict__ gfb, bf16* __restrict__ T5)
{
  __shared__ bf16 xs[64 * 136];        // 17.0 KB
  __shared__ bf16 stag[4][16 * 136];   // 17.0 KB
  const int tid = threadIdx.x;
  const int base = blockIdx.x * 64;
  const int w = tid >> 6, lane = tid & 63, g = lane >> 4, l15 = lane & 15;
  const int m = w & 3, half = w >> 2;

  const bf16* WFw = WF + (size_t)m * 16384 + (size_t)half * 8192;
  f32x4 af[16];
  #pragma unroll
  for (int f = 0; f < 16; ++f)
    af[f] = *(const f32x4*)(WFw + ((size_t)f*64 + lane)*8);

  // --- LayerNorm (8 threads per position, 16 floats each) ---
  {
    const int pl = tid >> 3, sub = tid & 7;
    const float4* src = (const float4*)(pr + (size_t)(base + pl) * 128 + sub * 16);
    float4 r[4];
    float s = 0.f, ss = 0.f;
    #pragma unroll
    for (int j = 0; j < 4; ++j) {
      r[j] = src[j];
      s  += r[j].x + r[j].y + r[j].z + r[j].w;
      ss += r[j].x*r[j].x + r[j].y*r[j].y + r[j].z*r[j].z + r[j].w*r[j].w;
    }
    s  += __shfl_xor(s, 1, 8);  s  += __shfl_xor(s, 2, 8);  s  += __shfl_xor(s, 4, 8);
    ss += __shfl_xor(ss, 1, 8); ss += __shfl_xor(ss, 2, 8); ss += __shfl_xor(ss, 4, 8);
    const float mu   = s * 0.0078125f;
    const float var  = ss * 0.0078125f - mu * mu;
    const float rstd = rsqrtf(var + 1e-5f);
    const float4* g4 = (const float4*)(gamma + sub * 16);
    const float4* b4 = (const float4*)(beta + sub * 16);
    bf16* xr = xs + pl * 136 + sub * 16;
    #pragma unroll
    for (int i = 0; i < 2; ++i) {
      float4 r0 = r[2*i], r1 = r[2*i+1];
      float4 gg0 = g4[2*i], gg1 = g4[2*i+1], bb0 = b4[2*i], bb1 = b4[2*i+1];
      bf16x8 o;
      o[0] = (bf16)((r0.x - mu) * rstd * gg0.x + bb0.x);
      o[1] = (bf16)((r0.y - mu) * rstd * gg0.y + bb0.y);
      o[2] = (bf16)((r0.z - mu) * rstd * gg0.z + bb0.z);
      o[3] = (bf16)((r0.w - mu) * rstd * gg0.w + bb0.w);
      o[4] = (bf16)((r1.x - mu) * rstd * gg1.x + bb1.x);
      o[5] = (bf16)((r1.y - mu) * rstd * gg1.y + bb1.y);
      o[6] = (bf16)((r1.z - mu) * rstd * gg1.z + bb1.z);
      o[7] = (bf16)((r1.w - mu) * rstd * gg1.w + bb1.w);
      *(bf16x8*)(xr + 8 * i) = o;
    }
  }

  #pragma unroll
  for (int f = 0; f < 16; ++f)
    asm volatile("" : "+v"(af[f]));

  __syncthreads();

  const f32x4 z = {0.f, 0.f, 0.f, 0.f};

  // --- pair_bias via MFMA -> fused T5 write (mask + pb), k_bias eliminated
  if (w < 4) {
    f32x4 acc = z;
    #pragma unroll
    for (int kt = 0; kt < 4; ++kt) {
      bf16x8 a = *(const bf16x8*)(WbF + ((size_t)kt*64 + lane)*8);
      bf16x8 b = *(const bf16x8*)(xs + (16*w + l15)*136 + 32*kt + 8*g);
      acc = MFMA(a, b, acc);
    }
    if (g == 0) {
      const int pos = base + 16*w + l15;
      const float mv = mask[pos];
      T5[pos]            = (bf16)(mv + acc[0]);
      T5[pos +   65536]  = (bf16)(mv + acc[1]);
      T5[pos + 2*65536]  = (bf16)(mv + acc[2]);
      T5[pos + 3*65536]  = (bf16)(mv + acc[3]);
    }
  }

  bf16* stw = stag[m];
  bf16* dst = (m == 0) ? qb : (m == 1) ? kb : (m == 2) ? vb : gfb;

  for (int nt = 0; nt < 4; ++nt) {
    bf16x8 bfr[4];
    #pragma unroll
    for (int kt = 0; kt < 4; ++kt)
      bfr[kt] = *(const bf16x8*)(xs + (16*nt + l15)*136 + 32*kt + 8*g);
    f32x4 acc[4];
    #pragma unroll
    for (int mtl = 0; mtl < 4; ++mtl) acc[mtl] = z;
    #pragma unroll
    for (int kt = 0; kt < 4; ++kt)
      #pragma unroll
      for (int mtl = 0; mtl < 4; ++mtl)
        acc[mtl] = MFMA(__builtin_bit_cast(bf16x8, af[mtl*4 + kt]), bfr[kt], acc[mtl]);

    #pragma unroll
    for (int mtl = 0; mtl < 4; ++mtl) {
      const int col = half*64 + 16*mtl + 4*g;
      f32x4 vv = acc[mtl];
      if (m == 3) {
        float4 bb = *(const float4*)(bfu + col);
        vv[0] = 1.f / (1.f + __expf(-(vv[0] + bb.x)));
        vv[1] = 1.f / (1.f + __expf(-(vv[1] + bb.y)));
        vv[2] = 1.f / (1.f + __expf(-(vv[2] + bb.z)));
        vv[3] = 1.f / (1.f + __expf(-(vv[3] + bb.w)));
      }
      bf16x4 o;
      o[0] = (bf16)vv[0]; o[1] = (bf16)vv[1]; o[2] = (bf16)vv[2]; o[3] = (bf16)vv[3];
      *(bf16x4*)(stw + l15*136 + col) = o;
    }

    // position-major store: one 128B-contiguous segment per position half-row
    #pragma unroll
    for (int i = 0; i < 2; ++i) {
      const int flat = i*512 + lane*8;
      const int p = flat >> 6, cf = half*64 + (flat & 63);
      bf16x8 val = *(const bf16x8*)(stw + p*136 + cf);
      *(bf16x8*)(dst + ((size_t)(base + 16*nt + p))*128 + cf) = val;
    }
  }
}

// ---------------------------------------------------------------------------
// k_attn: block=(s,h), 512 threads = 8 waves x 32 q-rows (2 q-tiles/wave).
// r5-proven compute structure; position-major [P][128] q/k/v inputs. NEW:
// after the av hoist vT is dead -> reused as a 256x32 output staging tile, so
// the aob store becomes one cooperative 16KB fully-contiguous write into
// head-major aob[h][P][32] (was 8B-granule scatter).
// ---------------------------------------------------------------------------
__global__ __launch_bounds__(512) void k_attn(
    const bf16* __restrict__ qb, const bf16* __restrict__ kb,
    const bf16* __restrict__ vb, const bf16* __restrict__ T5,
    bf16* __restrict__ aob)
{
  __shared__ bf16 qs[256 * 40];   // 20.0 KB, slot-permuted q-projection
  __shared__ bf16 vT[32 * 264];   // 16.5 KB, swizzled V^T; reused as ao stage
  const int tid = threadIdx.x;    // 0..511
  const int s = blockIdx.x >> 2, h = blockIdx.x & 3;
  const int rb = s * 256;
  const int hc = 32 * h;          // head column offset
  const bf16* T5h = T5 + (size_t)h * 65536;

  const int w = tid >> 6, lane = tid & 63, g = lane >> 4, l15 = lane & 15;

  // stage q (slot-permuted rows, stride 40) and vT (swizzled transpose)
  #pragma unroll
  for (int i = 0; i < 2; ++i) {
    const int flat = i*4096 + tid*8;
    const int pos = flat >> 5, cc = flat & 31;
    const int slot = (pos & 0xE3) | ((pos & 0x04) << 2) | ((pos & 0x18) >> 1);
    bf16x8 qv = *(const bf16x8*)(qb + ((size_t)rb + pos)*128 + hc + cc);
    *(bf16x8*)(qs + slot*40 + cc) = qv;
    bf16x8 vv = *(const bf16x8*)(vb + ((size_t)rb + pos)*128 + hc + cc);
    #pragma unroll
    for (int j = 0; j < 8; ++j) {
      const int row = cc + j;
      const int a = row >> 3;
      const int X = (a << 5) | ((a >> 1) << 4);
      vT[row*264 + (pos ^ X)] = vv[j];
    }
  }

  // prefetch both q-tiles' k-row B-fragments (global, independent of LDS)
  bf16x8 bq0 = *(const bf16x8*)(kb + ((size_t)rb + w*32 +      l15)*128 + hc + 8*g);
  bf16x8 bq1 = *(const bf16x8*)(kb + ((size_t)rb + w*32 + 16 + l15)*128 + hc + 8*g);

  __syncthreads();

  // hoist PV A-fragments from swizzled vT (once per block)
  bf16x8 av[2][8];
  #pragma unroll
  for (int mt = 0; mt < 2; ++mt) {
    const int row = 16*mt + l15;
    const int a = row >> 3;
    const int X = (a << 5) | ((a >> 1) << 4);
    #pragma unroll
    for (int kt = 0; kt < 8; ++kt)
      av[mt][kt] = *(const bf16x8*)(vT + row*264 + ((32*kt + 8*g) ^ X));
  }

  __syncthreads();               // all waves done reading vT -> reuse as stage
  bf16* aost = vT;               // [256][32] row-major, 64B rows

  const f32x4 z = {0.f, 0.f, 0.f, 0.f};

  #pragma unroll
  for (int qt = 0; qt < 2; ++qt) {
    const int q = w*32 + qt*16 + l15;
    const bf16x8 bq = qt ? bq1 : bq0;
    const bf16* Trow = T5h + (size_t)q * 256 + 8*g;
    f32x4 o0a = z, o0b = z, o1a = z, o1b = z;
    float rs = 0.f;
    #pragma unroll
    for (int kt = 0; kt < 8; ++kt) {
      bf16x8 a0 = *(const bf16x8*)(qs + (16*(2*kt + 0) + l15)*40 + 8*g);
      bf16x8 a1 = *(const bf16x8*)(qs + (16*(2*kt + 1) + l15)*40 + 8*g);
      f32x4 s0 = MFMA(a0, bq, z);
      f32x4 s1 = MFMA(a1, bq, z);
      bf16x4 b0 = *(const bf16x4*)(Trow + 32*kt);
      bf16x4 b1 = *(const bf16x4*)(Trow + 32*kt + 4);
      bf16x8 pf;
      #pragma unroll
      for (int r = 0; r < 4; ++r) {
        float e0 = __expf(s0[r] + (float)b0[r]);
        float e1 = __expf(s1[r] + (float)b1[r]);
        pf[r]     = (bf16)e0;
        pf[4 + r] = (bf16)e1;
        rs += e0 + e1;   // unrounded sum (matches f32 reference more closely)
      }
      if (kt & 1) {
        o0b = MFMA(av[0][kt], pf, o0b);
        o1b = MFMA(av[1][kt], pf, o1b);
      } else {
        o0a = MFMA(av[0][kt], pf, o0a);
        o1a = MFMA(av[1][kt], pf, o1a);
      }
    }
    rs += __shfl_xor(rs, 16);
    rs += __shfl_xor(rs, 32);
    const float inv = 1.f / rs;
    bf16x4 p0, p1;
    #pragma unroll
    for (int r = 0; r < 4; ++r) {
      p0[r] = (bf16)((o0a[r] + o0b[r]) * inv);
      p1[r] = (bf16)((o1a[r] + o1b[r]) * inv);
    }
    bf16* dst = aost + (size_t)q * 32;
    *(bf16x4*)(dst + 4*g)      = p0;
    *(bf16x4*)(dst + 16 + 4*g) = p1;
  }

  __syncthreads();   // staging complete

  // cooperative contiguous store: 16KB block -> head-major aob[h][rb..rb+256)
  bf16* aoh = aob + (size_t)h * P * 32;
  #pragma unroll
  for (int i = 0; i < 2; ++i) {
    const int flat = i*4096 + tid*8;
    const int pos = flat >> 5, cc = flat & 31;
    *(bf16x8*)(aoh + ((size_t)rb + pos)*32 + cc) =
        *(const bf16x8*)(aost + pos*32 + cc);
  }
}

// ---------------------------------------------------------------------------
// k_gate_out: 512 threads = 8 waves; wave j owns one 16-col output group
// (4 WoF frags = 16 regs, hoisted+pinned). aob head-major (r5-proven read),
// gfb position-major.
// ---------------------------------------------------------------------------
__global__ __launch_bounds__(512) void k_gate_out(
    const bf16* __restrict__ aob, const bf16* __restrict__ gfb,
    const bf16* __restrict__ WoF, const float* __restrict__ bo,
    float* __restrict__ out)
{
  __shared__ bf16 gs[64 * 136];
  const int tid = threadIdx.x;
  const int base = blockIdx.x * 64;
  const int w = tid >> 6, lane = tid & 63, g = lane >> 4, l15 = lane & 15;

  // hoist the wave's 4 WoF A-fragments (col group w, kt 0..3)
  f32x4 wf[4];
  #pragma unroll
  for (int kt = 0; kt < 4; ++kt)
    wf[kt] = *(const f32x4*)(WoF + ((size_t)(w*4 + kt)*64 + lane)*8);

  #pragma unroll
  for (int i = 0; i < 2; ++i) {
    const int flat = i*4096 + tid*8;
    const int pos = flat >> 7, c = flat & 127, h = c >> 5;
    bf16x8 a = *(const bf16x8*)(aob + ((size_t)h*P + base + pos)*32 + (c & 31));
    bf16x8 f = *(const bf16x8*)(gfb + ((size_t)(base + pos))*128 + c);
    bf16x8 o;
    #pragma unroll
    for (int j = 0; j < 8; ++j) o[j] = (bf16)((float)a[j] * (float)f[j]);
    *(bf16x8*)(gs + pos*136 + c) = o;
  }

  #pragma unroll
  for (int kt = 0; kt < 4; ++kt)
    asm volatile("" : "+v"(wf[kt]));

  __syncthreads();

  const f32x4 z = {0.f, 0.f, 0.f, 0.f};
  const int col = 16*w + 4*g;
  const float4 bb = *(const float4*)(bo + col);

  for (int nt = 0; nt < 4; ++nt) {
    bf16x8 bfr[4];
    #pragma unroll
    for (int kt = 0; kt < 4; ++kt)
      bfr[kt] = *(const bf16x8*)(gs + (16*nt + l15)*136 + 32*kt + 8*g);
    f32x4 a0 = z;
    #pragma unroll
    for (int kt = 0; kt < 4; ++kt)
      a0 = MFMA(__builtin_bit_cast(bf16x8, wf[kt]), bfr[kt], a0);
    const int pos = base + 16*nt + l15;
    *(float4*)(out + (size_t)pos*128 + col) =
        make_float4(a0[0] + bb.x, a0[1] + bb.y, a0[2] + bb.z, a0[3] + bb.w);
  }
}

// ---------------------------------------------------------------------------
extern "C" void kernel_launch(void* const* d_in, const int* in_sizes, int n_in,
                              void* d_out, int out_size, void* d_ws, size_t ws_size,
                              hipStream_t stream) {
  const float* pr    = (const float*)d_in[0];
  const float* mask  = (const float*)d_in[1];
  const float* gamma = (const float*)d_in[2];
  const float* beta  = (const float*)d_in[3];
  const float* Wq    = (const float*)d_in[4];
  const float* Wk    = (const float*)d_in[5];
  const float* Wv    = (const float*)d_in[6];
  const float* Wb    = (const float*)d_in[7];
  const float* Wfu   = (const float*)d_in[8];
  const float* bfu   = (const float*)d_in[9];
  const float* Wo    = (const float*)d_in[10];
  const float* bo    = (const float*)d_in[11];
  float* out = (float*)d_out;

  bf16* qb  = (bf16*)d_ws;                        // P*128
  bf16* kb  = qb  + (size_t)P * 128;
  bf16* vb  = kb  + (size_t)P * 128;
  bf16* gfb = vb  + (size_t)P * 128;              // P*128
  bf16* aob = gfb + (size_t)P * 128;              // H*P*32 (head-major)
  bf16* T5  = aob + (size_t)P * 128;              // H*P
  bf16* WF  = T5  + (size_t)H * P;                // 4*16384
  bf16* WoF = WF  + 4 * 16384;                    // 16384
  bf16* WbF = WoF + 16384;                        // 2048

  k_prep<<<41, 256, 0, stream>>>(Wq, Wk, Wv, Wfu, Wo, Wb, WF, WoF, WbF);
  k_ln_proj<<<1024, 512, 0, stream>>>(pr, gamma, beta, bfu, WF, WbF, mask,
                                      qb, kb, vb, gfb, T5);
  k_attn<<<1024, 512, 0, stream>>>(qb, kb, vb, T5, aob);
  k_gate_out<<<1024, 512, 0, stream>>>(aob, gfb, WoF, bo, out);
}

// Round 12
// 164.148 us; speedup vs baseline: 1.0564x; 1.0564x over previous
//
#include <hip/hip_runtime.h>
#include <math.h>

#define L 256
#define E 128
#define H 4
#define C 32
#define P (L*L)  // 65536

typedef __bf16 bf16;
typedef __bf16 bf16x8 __attribute__((ext_vector_type(8)));
typedef __bf16 bf16x4 __attribute__((ext_vector_type(4)));
typedef float  f32x4  __attribute__((ext_vector_type(4)));

#define MFMA(a,b,c) __builtin_amdgcn_mfma_f32_16x16x32_bf16((a),(b),(c),0,0,0)

// ---------------------------------------------------------------------------
// k_prep: emit weights in MFMA A-fragment order. Grid 41: blocks 0..39 cover
// (m, frag-quad) with one fragment per wave; block 40 builds WbF.
// ---------------------------------------------------------------------------
__global__ __launch_bounds__(256) void k_prep(
    const float* __restrict__ Wq, const float* __restrict__ Wk,
    const float* __restrict__ Wv, const float* __restrict__ Wfu,
    const float* __restrict__ Wo, const float* __restrict__ Wb,
    bf16* __restrict__ WF, bf16* __restrict__ WoF, bf16* __restrict__ WbF)
{
  const int b = blockIdx.x;  // 0..40
  const int lane = threadIdx.x & 63, wv = threadIdx.x >> 6;
  const int g = lane >> 4, l15 = lane & 15;
  if (b < 40) {
    const int m = b >> 3;
    const int f = (b & 7) * 4 + wv;
    const float* W = (m==0)?Wq:(m==1)?Wk:(m==2)?Wv:(m==3)?Wfu:Wo;
    bf16* dst = (m < 4) ? (WF + (size_t)m * 16384) : WoF;
    const float sc = (m == 0) ? 0.17677669529663689f : 1.0f;
    const int mt = f >> 2, kt = f & 3;
    const int row = 16*mt + l15, k0 = 32*kt + 8*g;
    bf16x8 o;
    #pragma unroll
    for (int j = 0; j < 8; ++j) o[j] = (bf16)(W[(size_t)(k0+j)*128 + row] * sc);
    *(bf16x8*)(dst + ((size_t)f*64 + lane)*8) = o;
  } else {
    const int kt = wv, k0 = 32*kt + 8*g;
    bf16x8 o;
    #pragma unroll
    for (int j = 0; j < 8; ++j)
      o[j] = (l15 < 4) ? (bf16)Wb[(size_t)(k0+j)*4 + l15] : (bf16)0.0f;
    *(bf16x8*)(WbF + ((size_t)kt*64 + lane)*8) = o;
  }
}

// ---------------------------------------------------------------------------
// k_ln_proj: r5-proven structure (512 thr = 8 waves, 64 pos/block, head-major
// qkv outputs) with two fixes:
// (1) PER-HEAD-PLANE stores: lane (p=lane>>2, c=(lane&3)*8) writes 64x16B =
//     1KB fully-contiguous per instruction into [h][P][32] -- r5's loop
//     sliced rows across two head planes per instruction (64B granule,
//     2.0 TB/s); this keeps attn's preferred layout at full write efficiency.
// (2) fused T5 write from the pair-bias MFMA regs (k_bias kernel eliminated).
// ---------------------------------------------------------------------------
__global__ __launch_bounds__(512) void k_ln_proj(
    const float* __restrict__ pr, const float* __restrict__ gamma,
    const float* __restrict__ beta, const float* __restrict__ bfu,
    const bf16* __restrict__ WF, const bf16* __restrict__ WbF,
    const float* __restrict__ mask,
    bf16* __restrict__ qbh, bf16* __restrict__ kbh, bf16* __restrict__ vbh,
    bf16* __restrict__ gfb, bf16* __restrict__ T5)
{
  __shared__ bf16 xs[64 * 136];        // 17.0 KB
  __shared__ bf16 stag[4][16 * 136];   // 17.0 KB
  const int tid = threadIdx.x;
  const int base = blockIdx.x * 64;
  const int w = tid >> 6, lane = tid & 63, g = lane >> 4, l15 = lane & 15;
  const int m = w & 3, half = w >> 2;

  const bf16* WFw = WF + (size_t)m * 16384 + (size_t)half * 8192;
  f32x4 af[16];
  #pragma unroll
  for (int f = 0; f < 16; ++f)
    af[f] = *(const f32x4*)(WFw + ((size_t)f*64 + lane)*8);

  // --- LayerNorm (8 threads per position, 16 floats each) ---
  {
    const int pl = tid >> 3, sub = tid & 7;
    const float4* src = (const float4*)(pr + (size_t)(base + pl) * 128 + sub * 16);
    float4 r[4];
    float s = 0.f, ss = 0.f;
    #pragma unroll
    for (int j = 0; j < 4; ++j) {
      r[j] = src[j];
      s  += r[j].x + r[j].y + r[j].z + r[j].w;
      ss += r[j].x*r[j].x + r[j].y*r[j].y + r[j].z*r[j].z + r[j].w*r[j].w;
    }
    s  += __shfl_xor(s, 1, 8);  s  += __shfl_xor(s, 2, 8);  s  += __shfl_xor(s, 4, 8);
    ss += __shfl_xor(ss, 1, 8); ss += __shfl_xor(ss, 2, 8); ss += __shfl_xor(ss, 4, 8);
    const float mu   = s * 0.0078125f;
    const float var  = ss * 0.0078125f - mu * mu;
    const float rstd = rsqrtf(var + 1e-5f);
    const float4* g4 = (const float4*)(gamma + sub * 16);
    const float4* b4 = (const float4*)(beta + sub * 16);
    bf16* xr = xs + pl * 136 + sub * 16;
    #pragma unroll
    for (int i = 0; i < 2; ++i) {
      float4 r0 = r[2*i], r1 = r[2*i+1];
      float4 gg0 = g4[2*i], gg1 = g4[2*i+1], bb0 = b4[2*i], bb1 = b4[2*i+1];
      bf16x8 o;
      o[0] = (bf16)((r0.x - mu) * rstd * gg0.x + bb0.x);
      o[1] = (bf16)((r0.y - mu) * rstd * gg0.y + bb0.y);
      o[2] = (bf16)((r0.z - mu) * rstd * gg0.z + bb0.z);
      o[3] = (bf16)((r0.w - mu) * rstd * gg0.w + bb0.w);
      o[4] = (bf16)((r1.x - mu) * rstd * gg1.x + bb1.x);
      o[5] = (bf16)((r1.y - mu) * rstd * gg1.y + bb1.y);
      o[6] = (bf16)((r1.z - mu) * rstd * gg1.z + bb1.z);
      o[7] = (bf16)((r1.w - mu) * rstd * gg1.w + bb1.w);
      *(bf16x8*)(xr + 8 * i) = o;
    }
  }

  #pragma unroll
  for (int f = 0; f < 16; ++f)
    asm volatile("" : "+v"(af[f]));

  __syncthreads();

  const f32x4 z = {0.f, 0.f, 0.f, 0.f};

  // --- pair_bias via MFMA -> fused T5 write (mask + pb), k_bias eliminated
  if (w < 4) {
    f32x4 acc = z;
    #pragma unroll
    for (int kt = 0; kt < 4; ++kt) {
      bf16x8 a = *(const bf16x8*)(WbF + ((size_t)kt*64 + lane)*8);
      bf16x8 b = *(const bf16x8*)(xs + (16*w + l15)*136 + 32*kt + 8*g);
      acc = MFMA(a, b, acc);
    }
    if (g == 0) {
      const int pos = base + 16*w + l15;
      const float mv = mask[pos];
      T5[pos]            = (bf16)(mv + acc[0]);
      T5[pos +   65536]  = (bf16)(mv + acc[1]);
      T5[pos + 2*65536]  = (bf16)(mv + acc[2]);
      T5[pos + 3*65536]  = (bf16)(mv + acc[3]);
    }
  }

  bf16* stw = stag[m];

  for (int nt = 0; nt < 4; ++nt) {
    bf16x8 bfr[4];
    #pragma unroll
    for (int kt = 0; kt < 4; ++kt)
      bfr[kt] = *(const bf16x8*)(xs + (16*nt + l15)*136 + 32*kt + 8*g);
    f32x4 acc[4];
    #pragma unroll
    for (int mtl = 0; mtl < 4; ++mtl) acc[mtl] = z;
    #pragma unroll
    for (int kt = 0; kt < 4; ++kt)
      #pragma unroll
      for (int mtl = 0; mtl < 4; ++mtl)
        acc[mtl] = MFMA(__builtin_bit_cast(bf16x8, af[mtl*4 + kt]), bfr[kt], acc[mtl]);

    // epilogue -> LDS staging (cols 64*half + 16*mtl + 4g, pos l15)
    #pragma unroll
    for (int mtl = 0; mtl < 4; ++mtl) {
      const int col = half*64 + 16*mtl + 4*g;
      f32x4 vv = acc[mtl];
      if (m == 3) {
        float4 bb = *(const float4*)(bfu + col);
        vv[0] = 1.f / (1.f + __expf(-(vv[0] + bb.x)));
        vv[1] = 1.f / (1.f + __expf(-(vv[1] + bb.y)));
        vv[2] = 1.f / (1.f + __expf(-(vv[2] + bb.z)));
        vv[3] = 1.f / (1.f + __expf(-(vv[3] + bb.w)));
      }
      bf16x4 o;
      o[0] = (bf16)vv[0]; o[1] = (bf16)vv[1]; o[2] = (bf16)vv[2]; o[3] = (bf16)vv[3];
      *(bf16x4*)(stw + l15*136 + col) = o;
    }

    if (m == 3) {
      // gate: position-major [P][128], 128B contiguous per position half-row
      #pragma unroll
      for (int i = 0; i < 2; ++i) {
        const int flat = i*512 + lane*8;
        const int p = flat >> 6, cf = half*64 + (flat & 63);
        bf16x8 val = *(const bf16x8*)(stw + p*136 + cf);
        *(bf16x8*)(gfb + ((size_t)(base + 16*nt + p))*128 + cf) = val;
      }
    } else {
      // q/k/v: head-major [h][P][32], ONE 1KB-contiguous store per plane
      bf16* dsth = (m == 0) ? qbh : (m == 1) ? kbh : vbh;
      const int p = lane >> 2, c = (lane & 3) * 8;
      #pragma unroll
      for (int hp = 0; hp < 2; ++hp) {
        const int h = 2*half + hp;
        bf16x8 val = *(const bf16x8*)(stw + p*136 + h*32 + c);
        *(bf16x8*)(dsth + ((size_t)h*P + base + 16*nt + p)*32 + c) = val;
      }
    }
  }
}

// ---------------------------------------------------------------------------
// k_attn: block=(s,h), 512 threads = 8 waves x 32 q-rows (2 q-tiles/wave).
// Swapped QK^T orientation; P lane-local; softmax via 2 shfl_xor on the
// unrounded exp sums; vT swizzle spreads the 4 tid&3 sub-groups onto bank
// offsets {0,16,8,24}; k-row B-frags prefetched; o-accumulators split 2-way.
// (r5-proven version, byte-identical)
// ---------------------------------------------------------------------------
__global__ __launch_bounds__(512) void k_attn(
    const bf16* __restrict__ qbh, const bf16* __restrict__ kbh,
    const bf16* __restrict__ vbh, const bf16* __restrict__ T5,
    bf16* __restrict__ aob)
{
  __shared__ bf16 qs[256 * 40];   // 20.0 KB, slot-permuted q-projection
  __shared__ bf16 vT[32 * 264];   // 16.5 KB, swizzled V^T
  const int tid = threadIdx.x;    // 0..511
  const int s = blockIdx.x >> 2, h = blockIdx.x & 3;
  const int rb = s * 256;
  const bf16* qh = qbh + (size_t)h * P * 32;
  const bf16* kh = kbh + (size_t)h * P * 32;
  const bf16* vh = vbh + (size_t)h * P * 32;
  const bf16* T5h = T5 + (size_t)h * 65536;

  const int w = tid >> 6, lane = tid & 63, g = lane >> 4, l15 = lane & 15;

  // stage q (slot-permuted rows, stride 40) and vT (swizzled transpose)
  #pragma unroll
  for (int i = 0; i < 2; ++i) {
    const int flat = i*4096 + tid*8;
    const int pos = flat >> 5, cc = flat & 31;
    const int slot = (pos & 0xE3) | ((pos & 0x04) << 2) | ((pos & 0x18) >> 1);
    bf16x8 qv = *(const bf16x8*)(qh + ((size_t)rb + pos)*32 + cc);
    *(bf16x8*)(qs + slot*40 + cc) = qv;
    bf16x8 vv = *(const bf16x8*)(vh + ((size_t)rb + pos)*32 + cc);
    #pragma unroll
    for (int j = 0; j < 8; ++j) {
      const int row = cc + j;
      const int a = row >> 3;
      const int X = (a << 5) | ((a >> 1) << 4);
      vT[row*264 + (pos ^ X)] = vv[j];
    }
  }

  // prefetch both q-tiles' k-row B-fragments (global, independent of LDS)
  bf16x8 bq0 = *(const bf16x8*)(kh + ((size_t)rb + w*32 +      l15)*32 + 8*g);
  bf16x8 bq1 = *(const bf16x8*)(kh + ((size_t)rb + w*32 + 16 + l15)*32 + 8*g);

  __syncthreads();

  // hoist PV A-fragments from swizzled vT (once per block)
  bf16x8 av[2][8];
  #pragma unroll
  for (int mt = 0; mt < 2; ++mt) {
    const int row = 16*mt + l15;
    const int a = row >> 3;
    const int X = (a << 5) | ((a >> 1) << 4);
    #pragma unroll
    for (int kt = 0; kt < 8; ++kt)
      av[mt][kt] = *(const bf16x8*)(vT + row*264 + ((32*kt + 8*g) ^ X));
  }

  bf16* aoh = aob + (size_t)h * P * 32;
  const f32x4 z = {0.f, 0.f, 0.f, 0.f};

  #pragma unroll
  for (int qt = 0; qt < 2; ++qt) {
    const int q = w*32 + qt*16 + l15;
    const bf16x8 bq = qt ? bq1 : bq0;
    const bf16* Trow = T5h + (size_t)q * 256 + 8*g;
    f32x4 o0a = z, o0b = z, o1a = z, o1b = z;
    float rs = 0.f;
    #pragma unroll
    for (int kt = 0; kt < 8; ++kt) {
      bf16x8 a0 = *(const bf16x8*)(qs + (16*(2*kt + 0) + l15)*40 + 8*g);
      bf16x8 a1 = *(const bf16x8*)(qs + (16*(2*kt + 1) + l15)*40 + 8*g);
      f32x4 s0 = MFMA(a0, bq, z);
      f32x4 s1 = MFMA(a1, bq, z);
      bf16x4 b0 = *(const bf16x4*)(Trow + 32*kt);
      bf16x4 b1 = *(const bf16x4*)(Trow + 32*kt + 4);
      bf16x8 pf;
      #pragma unroll
      for (int r = 0; r < 4; ++r) {
        float e0 = __expf(s0[r] + (float)b0[r]);
        float e1 = __expf(s1[r] + (float)b1[r]);
        pf[r]     = (bf16)e0;
        pf[4 + r] = (bf16)e1;
        rs += e0 + e1;   // unrounded sum (matches f32 reference more closely)
      }
      if (kt & 1) {
        o0b = MFMA(av[0][kt], pf, o0b);
        o1b = MFMA(av[1][kt], pf, o1b);
      } else {
        o0a = MFMA(av[0][kt], pf, o0a);
        o1a = MFMA(av[1][kt], pf, o1a);
      }
    }
    rs += __shfl_xor(rs, 16);
    rs += __shfl_xor(rs, 32);
    const float inv = 1.f / rs;
    bf16x4 p0, p1;
    #pragma unroll
    for (int r = 0; r < 4; ++r) {
      p0[r] = (bf16)((o0a[r] + o0b[r]) * inv);
      p1[r] = (bf16)((o1a[r] + o1b[r]) * inv);
    }
    bf16* dst = aoh + ((size_t)rb + q)*32;
    *(bf16x4*)(dst + 4*g)      = p0;
    *(bf16x4*)(dst + 16 + 4*g) = p1;
  }
}

// ---------------------------------------------------------------------------
// k_gate_out: 512 threads = 8 waves; wave j owns one 16-col output group
// (4 WoF frags = 16 regs, hoisted+pinned); per-wave MFMA chain 16.
// (r5-proven version, byte-identical)
// ---------------------------------------------------------------------------
__global__ __launch_bounds__(512) void k_gate_out(
    const bf16* __restrict__ aob, const bf16* __restrict__ gfb,
    const bf16* __restrict__ WoF, const float* __restrict__ bo,
    float* __restrict__ out)
{
  __shared__ bf16 gs[64 * 136];
  const int tid = threadIdx.x;
  const int base = blockIdx.x * 64;
  const int w = tid >> 6, lane = tid & 63, g = lane >> 4, l15 = lane & 15;

  // hoist the wave's 4 WoF A-fragments (col group w, kt 0..3)
  f32x4 wf[4];
  #pragma unroll
  for (int kt = 0; kt < 4; ++kt)
    wf[kt] = *(const f32x4*)(WoF + ((size_t)(w*4 + kt)*64 + lane)*8);

  #pragma unroll
  for (int i = 0; i < 2; ++i) {
    const int flat = i*4096 + tid*8;
    const int pos = flat >> 7, c = flat & 127, h = c >> 5;
    bf16x8 a = *(const bf16x8*)(aob + ((size_t)h*P + base + pos)*32 + (c & 31));
    bf16x8 f = *(const bf16x8*)(gfb + ((size_t)(base + pos))*128 + c);
    bf16x8 o;
    #pragma unroll
    for (int j = 0; j < 8; ++j) o[j] = (bf16)((float)a[j] * (float)f[j]);
    *(bf16x8*)(gs + pos*136 + c) = o;
  }

  #pragma unroll
  for (int kt = 0; kt < 4; ++kt)
    asm volatile("" : "+v"(wf[kt]));

  __syncthreads();

  const f32x4 z = {0.f, 0.f, 0.f, 0.f};
  const int col = 16*w + 4*g;
  const float4 bb = *(const float4*)(bo + col);

  for (int nt = 0; nt < 4; ++nt) {
    bf16x8 bfr[4];
    #pragma unroll
    for (int kt = 0; kt < 4; ++kt)
      bfr[kt] = *(const bf16x8*)(gs + (16*nt + l15)*136 + 32*kt + 8*g);
    f32x4 a0 = z;
    #pragma unroll
    for (int kt = 0; kt < 4; ++kt)
      a0 = MFMA(__builtin_bit_cast(bf16x8, wf[kt]), bfr[kt], a0);
    const int pos = base + 16*nt + l15;
    *(float4*)(out + (size_t)pos*128 + col) =
        make_float4(a0[0] + bb.x, a0[1] + bb.y, a0[2] + bb.z, a0[3] + bb.w);
  }
}

// ---------------------------------------------------------------------------
extern "C" void kernel_launch(void* const* d_in, const int* in_sizes, int n_in,
                              void* d_out, int out_size, void* d_ws, size_t ws_size,
                              hipStream_t stream) {
  const float* pr    = (const float*)d_in[0];
  const float* mask  = (const float*)d_in[1];
  const float* gamma = (const float*)d_in[2];
  const float* beta  = (const float*)d_in[3];
  const float* Wq    = (const float*)d_in[4];
  const float* Wk    = (const float*)d_in[5];
  const float* Wv    = (const float*)d_in[6];
  const float* Wb    = (const float*)d_in[7];
  const float* Wfu   = (const float*)d_in[8];
  const float* bfu   = (const float*)d_in[9];
  const float* Wo    = (const float*)d_in[10];
  const float* bo    = (const float*)d_in[11];
  float* out = (float*)d_out;

  bf16* qbh = (bf16*)d_ws;                        // H*P*32
  bf16* kbh = qbh + (size_t)H * P * 32;
  bf16* vbh = kbh + (size_t)H * P * 32;
  bf16* gfb = vbh + (size_t)H * P * 32;           // P*128
  bf16* aob = gfb + (size_t)P * 128;              // H*P*32
  bf16* T5  = aob + (size_t)H * P * 32;           // H*P
  bf16* WF  = T5  + (size_t)H * P;                // 4*16384
  bf16* WoF = WF  + 4 * 16384;                    // 16384
  bf16* WbF = WoF + 16384;                        // 2048

  k_prep<<<41, 256, 0, stream>>>(Wq, Wk, Wv, Wfu, Wo, Wb, WF, WoF, WbF);
  k_ln_proj<<<1024, 512, 0, stream>>>(pr, gamma, beta, bfu, WF, WbF, mask,
                                      qbh, kbh, vbh, gfb, T5);
  k_attn<<<1024, 512, 0, stream>>>(qbh, kbh, vbh, T5, aob);
  k_gate_out<<<1024, 512, 0, stream>>>(aob, gfb, WoF, bo, out);
}

// Round 13
// 164.091 us; speedup vs baseline: 1.0568x; 1.0003x over previous
//
#include <hip/hip_runtime.h>
#include <math.h>

#define L 256
#define E 128
#define H 4
#define C 32
#define P (L*L)  // 65536

typedef __bf16 bf16;
typedef __bf16 bf16x8 __attribute__((ext_vector_type(8)));
typedef __bf16 bf16x4 __attribute__((ext_vector_type(4)));
typedef float  f32x4  __attribute__((ext_vector_type(4)));

#define MFMA(a,b,c) __builtin_amdgcn_mfma_f32_16x16x32_bf16((a),(b),(c),0,0,0)

// ---------------------------------------------------------------------------
// k_prep: emit weights in MFMA A-fragment order. Grid 41: blocks 0..39 cover
// (m, frag-quad) with one fragment per wave; block 40 builds WbF.
// ---------------------------------------------------------------------------
__global__ __launch_bounds__(256) void k_prep(
    const float* __restrict__ Wq, const float* __restrict__ Wk,
    const float* __restrict__ Wv, const float* __restrict__ Wfu,
    const float* __restrict__ Wo, const float* __restrict__ Wb,
    bf16* __restrict__ WF, bf16* __restrict__ WoF, bf16* __restrict__ WbF)
{
  const int b = blockIdx.x;  // 0..40
  const int lane = threadIdx.x & 63, wv = threadIdx.x >> 6;
  const int g = lane >> 4, l15 = lane & 15;
  if (b < 40) {
    const int m = b >> 3;
    const int f = (b & 7) * 4 + wv;
    const float* W = (m==0)?Wq:(m==1)?Wk:(m==2)?Wv:(m==3)?Wfu:Wo;
    bf16* dst = (m < 4) ? (WF + (size_t)m * 16384) : WoF;
    const float sc = (m == 0) ? 0.17677669529663689f : 1.0f;
    const int mt = f >> 2, kt = f & 3;
    const int row = 16*mt + l15, k0 = 32*kt + 8*g;
    bf16x8 o;
    #pragma unroll
    for (int j = 0; j < 8; ++j) o[j] = (bf16)(W[(size_t)(k0+j)*128 + row] * sc);
    *(bf16x8*)(dst + ((size_t)f*64 + lane)*8) = o;
  } else {
    const int kt = wv, k0 = 32*kt + 8*g;
    bf16x8 o;
    #pragma unroll
    for (int j = 0; j < 8; ++j)
      o[j] = (l15 < 4) ? (bf16)Wb[(size_t)(k0+j)*4 + l15] : (bf16)0.0f;
    *(bf16x8*)(WbF + ((size_t)kt*64 + lane)*8) = o;
  }
}

// ---------------------------------------------------------------------------
// k_ln_proj: r12-proven structure. NEW: xs stride 136 -> 140 so B-fragment
// ds_read_b128 banks are 6*l15 mod 32 = all-16-distinct (was 4*l15 mod 32 =
// 8 banks -> 4-8 way conflicts; the 1.245M conflict cycles). stag stays 136
// (its accesses are 2-way = free). Per-head-plane 1KB stores + fused T5.
// ---------------------------------------------------------------------------
__global__ __launch_bounds__(512) void k_ln_proj(
    const float* __restrict__ pr, const float* __restrict__ gamma,
    const float* __restrict__ beta, const float* __restrict__ bfu,
    const bf16* __restrict__ WF, const bf16* __restrict__ WbF,
    const float* __restrict__ mask,
    bf16* __restrict__ qbh, bf16* __restrict__ kbh, bf16* __restrict__ vbh,
    bf16* __restrict__ gfb, bf16* __restrict__ T5)
{
  __shared__ bf16 xs[64 * 140];        // 17.5 KB (conflict-free stride)
  __shared__ bf16 stag[4][16 * 136];   // 17.0 KB
  const int tid = threadIdx.x;
  const int base = blockIdx.x * 64;
  const int w = tid >> 6, lane = tid & 63, g = lane >> 4, l15 = lane & 15;
  const int m = w & 3, half = w >> 2;

  const bf16* WFw = WF + (size_t)m * 16384 + (size_t)half * 8192;
  f32x4 af[16];
  #pragma unroll
  for (int f = 0; f < 16; ++f)
    af[f] = *(const f32x4*)(WFw + ((size_t)f*64 + lane)*8);

  // --- LayerNorm (8 threads per position, 16 floats each) ---
  {
    const int pl = tid >> 3, sub = tid & 7;
    const float4* src = (const float4*)(pr + (size_t)(base + pl) * 128 + sub * 16);
    float4 r[4];
    float s = 0.f, ss = 0.f;
    #pragma unroll
    for (int j = 0; j < 4; ++j) {
      r[j] = src[j];
      s  += r[j].x + r[j].y + r[j].z + r[j].w;
      ss += r[j].x*r[j].x + r[j].y*r[j].y + r[j].z*r[j].z + r[j].w*r[j].w;
    }
    s  += __shfl_xor(s, 1, 8);  s  += __shfl_xor(s, 2, 8);  s  += __shfl_xor(s, 4, 8);
    ss += __shfl_xor(ss, 1, 8); ss += __shfl_xor(ss, 2, 8); ss += __shfl_xor(ss, 4, 8);
    const float mu   = s * 0.0078125f;
    const float var  = ss * 0.0078125f - mu * mu;
    const float rstd = rsqrtf(var + 1e-5f);
    const float4* g4 = (const float4*)(gamma + sub * 16);
    const float4* b4 = (const float4*)(beta + sub * 16);
    bf16* xr = xs + pl * 140 + sub * 16;
    #pragma unroll
    for (int i = 0; i < 2; ++i) {
      float4 r0 = r[2*i], r1 = r[2*i+1];
      float4 gg0 = g4[2*i], gg1 = g4[2*i+1], bb0 = b4[2*i], bb1 = b4[2*i+1];
      bf16x8 o;
      o[0] = (bf16)((r0.x - mu) * rstd * gg0.x + bb0.x);
      o[1] = (bf16)((r0.y - mu) * rstd * gg0.y + bb0.y);
      o[2] = (bf16)((r0.z - mu) * rstd * gg0.z + bb0.z);
      o[3] = (bf16)((r0.w - mu) * rstd * gg0.w + bb0.w);
      o[4] = (bf16)((r1.x - mu) * rstd * gg1.x + bb1.x);
      o[5] = (bf16)((r1.y - mu) * rstd * gg1.y + bb1.y);
      o[6] = (bf16)((r1.z - mu) * rstd * gg1.z + bb1.z);
      o[7] = (bf16)((r1.w - mu) * rstd * gg1.w + bb1.w);
      *(bf16x8*)(xr + 8 * i) = o;
    }
  }

  #pragma unroll
  for (int f = 0; f < 16; ++f)
    asm volatile("" : "+v"(af[f]));

  __syncthreads();

  const f32x4 z = {0.f, 0.f, 0.f, 0.f};

  // --- pair_bias via MFMA -> fused T5 write (mask + pb)
  if (w < 4) {
    f32x4 acc = z;
    #pragma unroll
    for (int kt = 0; kt < 4; ++kt) {
      bf16x8 a = *(const bf16x8*)(WbF + ((size_t)kt*64 + lane)*8);
      bf16x8 b = *(const bf16x8*)(xs + (16*w + l15)*140 + 32*kt + 8*g);
      acc = MFMA(a, b, acc);
    }
    if (g == 0) {
      const int pos = base + 16*w + l15;
      const float mv = mask[pos];
      T5[pos]            = (bf16)(mv + acc[0]);
      T5[pos +   65536]  = (bf16)(mv + acc[1]);
      T5[pos + 2*65536]  = (bf16)(mv + acc[2]);
      T5[pos + 3*65536]  = (bf16)(mv + acc[3]);
    }
  }

  bf16* stw = stag[m];

  for (int nt = 0; nt < 4; ++nt) {
    bf16x8 bfr[4];
    #pragma unroll
    for (int kt = 0; kt < 4; ++kt)
      bfr[kt] = *(const bf16x8*)(xs + (16*nt + l15)*140 + 32*kt + 8*g);
    f32x4 acc[4];
    #pragma unroll
    for (int mtl = 0; mtl < 4; ++mtl) acc[mtl] = z;
    #pragma unroll
    for (int kt = 0; kt < 4; ++kt)
      #pragma unroll
      for (int mtl = 0; mtl < 4; ++mtl)
        acc[mtl] = MFMA(__builtin_bit_cast(bf16x8, af[mtl*4 + kt]), bfr[kt], acc[mtl]);

    // epilogue -> LDS staging (cols 64*half + 16*mtl + 4g, pos l15)
    #pragma unroll
    for (int mtl = 0; mtl < 4; ++mtl) {
      const int col = half*64 + 16*mtl + 4*g;
      f32x4 vv = acc[mtl];
      if (m == 3) {
        float4 bb = *(const float4*)(bfu + col);
        vv[0] = 1.f / (1.f + __expf(-(vv[0] + bb.x)));
        vv[1] = 1.f / (1.f + __expf(-(vv[1] + bb.y)));
        vv[2] = 1.f / (1.f + __expf(-(vv[2] + bb.z)));
        vv[3] = 1.f / (1.f + __expf(-(vv[3] + bb.w)));
      }
      bf16x4 o;
      o[0] = (bf16)vv[0]; o[1] = (bf16)vv[1]; o[2] = (bf16)vv[2]; o[3] = (bf16)vv[3];
      *(bf16x4*)(stw + l15*136 + col) = o;
    }

    if (m == 3) {
      // gate: position-major [P][128], 128B contiguous per position half-row
      #pragma unroll
      for (int i = 0; i < 2; ++i) {
        const int flat = i*512 + lane*8;
        const int p = flat >> 6, cf = half*64 + (flat & 63);
        bf16x8 val = *(const bf16x8*)(stw + p*136 + cf);
        *(bf16x8*)(gfb + ((size_t)(base + 16*nt + p))*128 + cf) = val;
      }
    } else {
      // q/k/v: head-major [h][P][32], ONE 1KB-contiguous store per plane
      bf16* dsth = (m == 0) ? qbh : (m == 1) ? kbh : vbh;
      const int p = lane >> 2, c = (lane & 3) * 8;
      #pragma unroll
      for (int hp = 0; hp < 2; ++hp) {
        const int h = 2*half + hp;
        bf16x8 val = *(const bf16x8*)(stw + p*136 + h*32 + c);
        *(bf16x8*)(dsth + ((size_t)h*P + base + 16*nt + p)*32 + c) = val;
      }
    }
  }
}

// ---------------------------------------------------------------------------
// k_attn: block=(s,h), 512 threads = 8 waves x 32 q-rows (2 q-tiles/wave).
// r5/r12-proven structure. NEW: the two 8B T5 bias loads per kt are one
// aligned 16B region -> merged into a single bf16x8 load (halves the in-loop
// global load count).
// ---------------------------------------------------------------------------
__global__ __launch_bounds__(512) void k_attn(
    const bf16* __restrict__ qbh, const bf16* __restrict__ kbh,
    const bf16* __restrict__ vbh, const bf16* __restrict__ T5,
    bf16* __restrict__ aob)
{
  __shared__ bf16 qs[256 * 40];   // 20.0 KB, slot-permuted q-projection
  __shared__ bf16 vT[32 * 264];   // 16.5 KB, swizzled V^T
  const int tid = threadIdx.x;    // 0..511
  const int s = blockIdx.x >> 2, h = blockIdx.x & 3;
  const int rb = s * 256;
  const bf16* qh = qbh + (size_t)h * P * 32;
  const bf16* kh = kbh + (size_t)h * P * 32;
  const bf16* vh = vbh + (size_t)h * P * 32;
  const bf16* T5h = T5 + (size_t)h * 65536;

  const int w = tid >> 6, lane = tid & 63, g = lane >> 4, l15 = lane & 15;

  // stage q (slot-permuted rows, stride 40) and vT (swizzled transpose)
  #pragma unroll
  for (int i = 0; i < 2; ++i) {
    const int flat = i*4096 + tid*8;
    const int pos = flat >> 5, cc = flat & 31;
    const int slot = (pos & 0xE3) | ((pos & 0x04) << 2) | ((pos & 0x18) >> 1);
    bf16x8 qv = *(const bf16x8*)(qh + ((size_t)rb + pos)*32 + cc);
    *(bf16x8*)(qs + slot*40 + cc) = qv;
    bf16x8 vv = *(const bf16x8*)(vh + ((size_t)rb + pos)*32 + cc);
    #pragma unroll
    for (int j = 0; j < 8; ++j) {
      const int row = cc + j;
      const int a = row >> 3;
      const int X = (a << 5) | ((a >> 1) << 4);
      vT[row*264 + (pos ^ X)] = vv[j];
    }
  }

  // prefetch both q-tiles' k-row B-fragments (global, independent of LDS)
  bf16x8 bq0 = *(const bf16x8*)(kh + ((size_t)rb + w*32 +      l15)*32 + 8*g);
  bf16x8 bq1 = *(const bf16x8*)(kh + ((size_t)rb + w*32 + 16 + l15)*32 + 8*g);

  __syncthreads();

  // hoist PV A-fragments from swizzled vT (once per block)
  bf16x8 av[2][8];
  #pragma unroll
  for (int mt = 0; mt < 2; ++mt) {
    const int row = 16*mt + l15;
    const int a = row >> 3;
    const int X = (a << 5) | ((a >> 1) << 4);
    #pragma unroll
    for (int kt = 0; kt < 8; ++kt)
      av[mt][kt] = *(const bf16x8*)(vT + row*264 + ((32*kt + 8*g) ^ X));
  }

  bf16* aoh = aob + (size_t)h * P * 32;
  const f32x4 z = {0.f, 0.f, 0.f, 0.f};

  #pragma unroll
  for (int qt = 0; qt < 2; ++qt) {
    const int q = w*32 + qt*16 + l15;
    const bf16x8 bq = qt ? bq1 : bq0;
    const bf16* Trow = T5h + (size_t)q * 256 + 8*g;
    f32x4 o0a = z, o0b = z, o1a = z, o1b = z;
    float rs = 0.f;
    #pragma unroll
    for (int kt = 0; kt < 8; ++kt) {
      bf16x8 a0 = *(const bf16x8*)(qs + (16*(2*kt + 0) + l15)*40 + 8*g);
      bf16x8 a1 = *(const bf16x8*)(qs + (16*(2*kt + 1) + l15)*40 + 8*g);
      f32x4 s0 = MFMA(a0, bq, z);
      f32x4 s1 = MFMA(a1, bq, z);
      bf16x8 tb = *(const bf16x8*)(Trow + 32*kt);   // bias: one 16B load
      bf16x8 pf;
      #pragma unroll
      for (int r = 0; r < 4; ++r) {
        float e0 = __expf(s0[r] + (float)tb[r]);
        float e1 = __expf(s1[r] + (float)tb[4 + r]);
        pf[r]     = (bf16)e0;
        pf[4 + r] = (bf16)e1;
        rs += e0 + e1;   // unrounded sum (matches f32 reference more closely)
      }
      if (kt & 1) {
        o0b = MFMA(av[0][kt], pf, o0b);
        o1b = MFMA(av[1][kt], pf, o1b);
      } else {
        o0a = MFMA(av[0][kt], pf, o0a);
        o1a = MFMA(av[1][kt], pf, o1a);
      }
    }
    rs += __shfl_xor(rs, 16);
    rs += __shfl_xor(rs, 32);
    const float inv = 1.f / rs;
    bf16x4 p0, p1;
    #pragma unroll
    for (int r = 0; r < 4; ++r) {
      p0[r] = (bf16)((o0a[r] + o0b[r]) * inv);
      p1[r] = (bf16)((o1a[r] + o1b[r]) * inv);
    }
    bf16* dst = aoh + ((size_t)rb + q)*32;
    *(bf16x4*)(dst + 4*g)      = p0;
    *(bf16x4*)(dst + 16 + 4*g) = p1;
  }
}

// ---------------------------------------------------------------------------
// k_gate_out: 512 threads = 8 waves; wave j owns one 16-col output group
// (4 WoF frags = 16 regs, hoisted+pinned). NEW: gs stride 136 -> 140 (same
// all-16-banks-distinct fix as ln_proj's xs).
// ---------------------------------------------------------------------------
__global__ __launch_bounds__(512) void k_gate_out(
    const bf16* __restrict__ aob, const bf16* __restrict__ gfb,
    const bf16* __restrict__ WoF, const float* __restrict__ bo,
    float* __restrict__ out)
{
  __shared__ bf16 gs[64 * 140];   // 17.5 KB (conflict-free stride)
  const int tid = threadIdx.x;
  const int base = blockIdx.x * 64;
  const int w = tid >> 6, lane = tid & 63, g = lane >> 4, l15 = lane & 15;

  // hoist the wave's 4 WoF A-fragments (col group w, kt 0..3)
  f32x4 wf[4];
  #pragma unroll
  for (int kt = 0; kt < 4; ++kt)
    wf[kt] = *(const f32x4*)(WoF + ((size_t)(w*4 + kt)*64 + lane)*8);

  #pragma unroll
  for (int i = 0; i < 2; ++i) {
    const int flat = i*4096 + tid*8;
    const int pos = flat >> 7, c = flat & 127, h = c >> 5;
    bf16x8 a = *(const bf16x8*)(aob + ((size_t)h*P + base + pos)*32 + (c & 31));
    bf16x8 f = *(const bf16x8*)(gfb + ((size_t)(base + pos))*128 + c);
    bf16x8 o;
    #pragma unroll
    for (int j = 0; j < 8; ++j) o[j] = (bf16)((float)a[j] * (float)f[j]);
    *(bf16x8*)(gs + pos*140 + c) = o;
  }

  #pragma unroll
  for (int kt = 0; kt < 4; ++kt)
    asm volatile("" : "+v"(wf[kt]));

  __syncthreads();

  const f32x4 z = {0.f, 0.f, 0.f, 0.f};
  const int col = 16*w + 4*g;
  const float4 bb = *(const float4*)(bo + col);

  for (int nt = 0; nt < 4; ++nt) {
    bf16x8 bfr[4];
    #pragma unroll
    for (int kt = 0; kt < 4; ++kt)
      bfr[kt] = *(const bf16x8*)(gs + (16*nt + l15)*140 + 32*kt + 8*g);
    f32x4 a0 = z;
    #pragma unroll
    for (int kt = 0; kt < 4; ++kt)
      a0 = MFMA(__builtin_bit_cast(bf16x8, wf[kt]), bfr[kt], a0);
    const int pos = base + 16*nt + l15;
    *(float4*)(out + (size_t)pos*128 + col) =
        make_float4(a0[0] + bb.x, a0[1] + bb.y, a0[2] + bb.z, a0[3] + bb.w);
  }
}

// ---------------------------------------------------------------------------
extern "C" void kernel_launch(void* const* d_in, const int* in_sizes, int n_in,
                              void* d_out, int out_size, void* d_ws, size_t ws_size,
                              hipStream_t stream) {
  const float* pr    = (const float*)d_in[0];
  const float* mask  = (const float*)d_in[1];
  const float* gamma = (const float*)d_in[2];
  const float* beta  = (const float*)d_in[3];
  const float* Wq    = (const float*)d_in[4];
  const float* Wk    = (const float*)d_in[5];
  const float* Wv    = (const float*)d_in[6];
  const float* Wb    = (const float*)d_in[7];
  const float* Wfu   = (const float*)d_in[8];
  const float* bfu   = (const float*)d_in[9];
  const float* Wo    = (const float*)d_in[10];
  const float* bo    = (const float*)d_in[11];
  float* out = (float*)d_out;

  bf16* qbh = (bf16*)d_ws;                        // H*P*32
  bf16* kbh = qbh + (size_t)H * P * 32;
  bf16* vbh = kbh + (size_t)H * P * 32;
  bf16* gfb = vbh + (size_t)H * P * 32;           // P*128
  bf16* aob = gfb + (size_t)P * 128;              // H*P*32
  bf16* T5  = aob + (size_t)H * P * 32;           // H*P
  bf16* WF  = T5  + (size_t)H * P;                // 4*16384
  bf16* WoF = WF  + 4 * 16384;                    // 16384
  bf16* WbF = WoF + 16384;                        // 2048

  k_prep<<<41, 256, 0, stream>>>(Wq, Wk, Wv, Wfu, Wo, Wb, WF, WoF, WbF);
  k_ln_proj<<<1024, 512, 0, stream>>>(pr, gamma, beta, bfu, WF, WbF, mask,
                                      qbh, kbh, vbh, gfb, T5);
  k_attn<<<1024, 512, 0, stream>>>(qbh, kbh, vbh, T5, aob);
  k_gate_out<<<1024, 512, 0, stream>>>(aob, gfb, WoF, bo, out);
}